// Round 2
// baseline (388.694 us; speedup 1.0000x reference)
//
#include <hip/hip_runtime.h>

// Fully-fused ShuffleNet unit, fp32, NCHW. B=64, Cin=Cout=480, mid=120, H=W=28.
// Grid: 64 batches x 4 row-stripes (7 rows each) = 256 blocks = 1 per CU.
// Block: 768 threads. LDS holds conv1 output (stripe+halo), per-row-pair
// shuffled dw output, weights/BN params. Intermediates never touch HBM.

namespace {
constexpr int CIN  = 480;
constexpr int MID  = 120;
constexpr int HH   = 28;
constexpr int WW   = 28;
constexpr float EPSV = 1e-5f;
constexpr int MSTR = 253;               // mid row stride (odd -> no bank pathologies)
// LDS float counts
constexpr int N_MID = MID * MSTR;       // 30360
constexpr int N_T2  = MID * 56;         // 6720
constexpr int N_W2  = MID * 9;          // 1080
constexpr int SMEM_FLOATS = N_MID + N_T2 + N_W2 + 2*MID + 2*MID + 2*CIN; // 39600
constexpr int SMEM_BYTES  = SMEM_FLOATS * 4;   // 158400
}

__global__ __launch_bounds__(768) void fused_shufflenet(
    const float* __restrict__ x,
    const float* __restrict__ w1, const float* __restrict__ g1,
    const float* __restrict__ b1, const float* __restrict__ m1, const float* __restrict__ v1,
    const float* __restrict__ w2, const float* __restrict__ g2,
    const float* __restrict__ b2, const float* __restrict__ m2, const float* __restrict__ v2,
    const float* __restrict__ w3, const float* __restrict__ g3,
    const float* __restrict__ b3, const float* __restrict__ m3, const float* __restrict__ v3,
    float* __restrict__ out)
{
    extern __shared__ float sm[];
    float* mid = sm;                    // [120][MSTR]
    float* t2  = mid + N_MID;           // [120][56]   (post-shuffle, 2 rows)
    float* w2l = t2 + N_T2;             // [120][9]
    float* s1v = w2l + N_W2;  float* sh1 = s1v + MID;
    float* s2v = sh1 + MID;   float* sh2 = s2v + MID;
    float* s3v = sh2 + MID;   float* sh3 = s3v + CIN;

    const int tid = threadIdx.x;
    const int s   = blockIdx.x;         // stripe 0..3
    const int b   = blockIdx.y;         // batch 0..63
    const int r0  = s * 7;              // first output row of stripe
    const int rows_lo = (r0 - 1 < 0) ? 0 : r0 - 1;
    const int rows_hi = (r0 + 7 > 27) ? 27 : r0 + 7;
    const int nrow = rows_hi - rows_lo + 1;    // 8 or 9
    const int npx  = nrow * 28;

    // ---- stage BN params + dw weights into LDS ----
    if (tid < MID) {
        float sA = g1[tid] * rsqrtf(v1[tid] + EPSV);
        s1v[tid] = sA; sh1[tid] = fmaf(-m1[tid], sA, b1[tid]);
        float sB = g2[tid] * rsqrtf(v2[tid] + EPSV);
        s2v[tid] = sB; sh2[tid] = fmaf(-m2[tid], sB, b2[tid]);
    }
    if (tid < CIN) {
        float sC = g3[tid] * rsqrtf(v3[tid] + EPSV);
        s3v[tid] = sC; sh3[tid] = fmaf(-m3[tid], sC, b3[tid]);
    }
    for (int i = tid; i < N_W2; i += 768) w2l[i] = w2[i];
    __syncthreads();

    // ---- phase 1: conv1 (1x1, G=3) + BN + ReLU over stripe+halo ----
    {
        const int g  = tid >> 8;            // 0..2 (wave-uniform)
        const int px = tid & 255;           // pixel in halo window
        const bool act = px < npx;
        const int pxe = act ? px : 0;
        const float* __restrict__ xg =
            x + (((size_t)b * CIN + (size_t)g * 160) * HH + rows_lo) * WW;

        float acc[40];
#pragma unroll
        for (int c = 0; c < 40; ++c) acc[c] = 0.f;

        for (int ic4 = 0; ic4 < 40; ++ic4) {
            const float* xp = xg + (size_t)ic4 * 4 * 784 + pxe;
            const float x0 = xp[0];
            const float x1 = xp[784];
            const float x2 = xp[1568];
            const float x3 = xp[2352];
            const float* wp = w1 + g * 40 * 160 + ic4 * 4;
#pragma unroll
            for (int c = 0; c < 40; ++c) {
                const float4 wv = *reinterpret_cast<const float4*>(wp + c * 160);
                float a = acc[c];
                a = fmaf(x0, wv.x, a);
                a = fmaf(x1, wv.y, a);
                a = fmaf(x2, wv.z, a);
                a = fmaf(x3, wv.w, a);
                acc[c] = a;
            }
        }
        if (act) {
#pragma unroll
            for (int c = 0; c < 40; ++c) {
                const int mc = g * 40 + c;
                float v = fmaf(acc[c], s1v[mc], sh1[mc]);
                mid[mc * MSTR + px] = v > 0.f ? v : 0.f;
            }
        }
    }

    // ---- per row-pair: dw3x3+BN+shuffle -> t2 ; conv3+BN+ReLU+shortcut -> out ----
    for (int rp = 0; rp < 4; ++rp) {
        const int a0 = r0 + 2 * rp;
        __syncthreads();

        // dw for rows a0, a0+1 (row a0+1 masked on last pair)
        for (int i = tid; i < N_T2; i += 768) {
            const int c   = i / 56;
            const int p56 = i - c * 56;
            const int rof = p56 / 28;
            const int col = p56 - rof * 28;
            const int a   = a0 + rof;
            if (a <= r0 + 6) {
                float accd = 0.f;
#pragma unroll
                for (int dh = -1; dh <= 1; ++dh) {
                    const int aa = a + dh;
                    if (aa >= 0 && aa <= 27) {
                        const float* mrow = &mid[c * MSTR + (aa - rows_lo) * 28];
#pragma unroll
                        for (int dc = -1; dc <= 1; ++dc) {
                            const int cc = col + dc;
                            if (cc >= 0 && cc < 28)
                                accd = fmaf(mrow[cc], w2l[c * 9 + (dh + 1) * 3 + (dc + 1)], accd);
                        }
                    }
                }
                const float val = fmaf(accd, s2v[c], sh2[c]);
                const int gi = c / 40;
                const int cs = (c - gi * 40) * 3 + gi;   // channel shuffle
                t2[cs * 56 + p56] = val;
            }
        }
        __syncthreads();

        // conv3: wave w handles oc [w*40, w*40+40), lanes = 56 pixels of the row pair
        {
            const int wv   = tid >> 6;          // 0..11 (wave id)
            const int lane = tid & 63;
            const int prw  = lane / 28;         // 0,1 (>=2 inactive)
            const int col  = lane - prw * 28;
            const bool act = (lane < 56) && (2 * rp + prw < 7);
            const int pxe  = lane < 56 ? lane : 0;
            const int oc0  = wv * 40;           // wave-uniform
            const int gg   = wv >> 2;           // group 0..2

            float acc3[40];
#pragma unroll
            for (int c = 0; c < 40; ++c) acc3[c] = 0.f;

            for (int ic4 = 0; ic4 < 10; ++ic4) {
                const float* tp = &t2[(gg * 40 + ic4 * 4) * 56 + pxe];
                const float t0 = tp[0];
                const float t1 = tp[56];
                const float t2r = tp[112];
                const float t3 = tp[168];
                const float* wp = w3 + oc0 * 40 + ic4 * 4;
#pragma unroll
                for (int c = 0; c < 40; ++c) {
                    const float4 w4 = *reinterpret_cast<const float4*>(wp + c * 40);
                    float a = acc3[c];
                    a = fmaf(t0, w4.x, a);
                    a = fmaf(t1, w4.y, a);
                    a = fmaf(t2r, w4.z, a);
                    a = fmaf(t3, w4.w, a);
                    acc3[c] = a;
                }
            }
            if (act) {
                const size_t base = ((size_t)b * CIN + oc0) * 784
                                  + (size_t)(a0 + prw) * 28 + col;
#pragma unroll
                for (int c = 0; c < 40; ++c) {
                    const int oc = oc0 + c;
                    float v = fmaf(acc3[c], s3v[oc], sh3[oc]);
                    v = v > 0.f ? v : 0.f;
                    const size_t idx = base + (size_t)c * 784;
                    out[idx] = v + x[idx];
                }
            }
        }
    }
}

extern "C" void kernel_launch(void* const* d_in, const int* in_sizes, int n_in,
                              void* d_out, int out_size, void* d_ws, size_t ws_size,
                              hipStream_t stream) {
    const float* x  = (const float*)d_in[0];
    const float* w1 = (const float*)d_in[1];
    const float* g1 = (const float*)d_in[2];
    const float* b1 = (const float*)d_in[3];
    const float* m1 = (const float*)d_in[4];
    const float* v1 = (const float*)d_in[5];
    const float* w2 = (const float*)d_in[6];
    const float* g2 = (const float*)d_in[7];
    const float* b2 = (const float*)d_in[8];
    const float* m2 = (const float*)d_in[9];
    const float* v2 = (const float*)d_in[10];
    const float* w3 = (const float*)d_in[11];
    const float* g3 = (const float*)d_in[12];
    const float* b3 = (const float*)d_in[13];
    const float* m3 = (const float*)d_in[14];
    const float* v3 = (const float*)d_in[15];
    float* out = (float*)d_out;

    static bool attr_set = false;
    if (!attr_set) {
        hipFuncSetAttribute((const void*)fused_shufflenet,
                            hipFuncAttributeMaxDynamicSharedMemorySize, SMEM_BYTES);
        attr_set = true;
    }

    dim3 grid(4, 64, 1);
    fused_shufflenet<<<grid, 768, SMEM_BYTES, stream>>>(
        x, w1, g1, b1, m1, v1, w2, g2, b2, m2, v2, w3, g3, b3, m3, v3, out);
}

// Round 3
// 137.734 us; speedup vs baseline: 2.8221x; 2.8221x over previous
//
#include <hip/hip_runtime.h>

// ShuffleNet unit, fp32, NCHW. B=64, Cin=Cout=480, mid=120, H=W=28.
// 3 kernels; intermediates in d_ws. Multi-pixel threads for vector loads +
// ILP; weights indexed by blockIdx.y only -> scalar (SGPR) loads.

namespace {
constexpr int CIN = 480;
constexpr int MID = 120;
constexpr int HWP = 784;
constexpr float EPSV = 1e-5f;
}

// ---------- K1: 1x1 grouped conv (480->120, G=3) + BN + ReLU ----------
// thread: 2 adjacent px, 10 oc.  grid (98, 12)
__global__ __launch_bounds__(256, 4) void k1_conv1(
    const float* __restrict__ x,  const float* __restrict__ w1,
    const float* __restrict__ g1, const float* __restrict__ b1,
    const float* __restrict__ m1, const float* __restrict__ v1,
    float* __restrict__ tmp1)
{
    const int t   = blockIdx.x * 256 + threadIdx.x;   // 0..25087
    const int b   = t / 392;
    const int hw  = (t - b * 392) * 2;
    const int oc0 = blockIdx.y * 10;                  // uniform
    const int g   = oc0 / 40;
    const float* __restrict__ xp = x + (size_t)(b * CIN + g * 160) * HWP + hw;
    const float* __restrict__ wp = w1 + oc0 * 160;

    float acc0[10], acc1[10];
#pragma unroll
    for (int j = 0; j < 10; ++j) { acc0[j] = 0.f; acc1[j] = 0.f; }

#pragma unroll 4
    for (int ic = 0; ic < 160; ++ic) {
        const float2 xv = *reinterpret_cast<const float2*>(xp + ic * HWP);
#pragma unroll
        for (int j = 0; j < 10; ++j) {
            const float w = wp[j * 160 + ic];         // scalar load
            acc0[j] = fmaf(xv.x, w, acc0[j]);
            acc1[j] = fmaf(xv.y, w, acc1[j]);
        }
    }

    float* __restrict__ op = tmp1 + (size_t)(b * MID + oc0) * HWP + hw;
#pragma unroll
    for (int j = 0; j < 10; ++j) {
        const int oc = oc0 + j;
        const float s  = g1[oc] * rsqrtf(v1[oc] + EPSV);
        const float sh = fmaf(-m1[oc], s, b1[oc]);
        float2 o;
        o.x = fmaf(acc0[j], s, sh); o.x = o.x > 0.f ? o.x : 0.f;
        o.y = fmaf(acc1[j], s, sh); o.y = o.y > 0.f ? o.y : 0.f;
        *reinterpret_cast<float2*>(op + j * HWP) = o;
    }
}

// ---------- K2: depthwise 3x3 + BN, shuffle folded into write ----------
// thread: 4 adjacent px (same row), 1 channel.  grid (49, 120)
__global__ __launch_bounds__(256) void k2_dw(
    const float* __restrict__ tmp1, const float* __restrict__ w2,
    const float* __restrict__ g2,   const float* __restrict__ b2,
    const float* __restrict__ m2,   const float* __restrict__ v2,
    float* __restrict__ tmp2)
{
    const int t  = blockIdx.x * 256 + threadIdx.x;    // 0..12543
    const int b  = t / 196;
    const int hw = (t - b * 196) * 4;
    const int h  = hw / 28;
    const int w  = hw - h * 28;                       // 0,4,...,24
    const int c  = blockIdx.y;                        // uniform
    const float* __restrict__ in = tmp1 + (size_t)(b * MID + c) * HWP;

    float wk[9];
#pragma unroll
    for (int i = 0; i < 9; ++i) wk[i] = w2[c * 9 + i];  // scalar loads

    float a0 = 0.f, a1 = 0.f, a2 = 0.f, a3 = 0.f;
#pragma unroll
    for (int dh = -1; dh <= 1; ++dh) {
        const int hh = h + dh;
        if (hh < 0 || hh > 27) continue;
        const float* r = in + hh * 28 + w;
        const float4 c4 = *reinterpret_cast<const float4*>(r);
        const float cl = (w > 0)  ? r[-1] : 0.f;
        const float cr = (w < 24) ? r[4]  : 0.f;
        const float* wr = wk + (dh + 1) * 3;
        a0 = fmaf(cl,   wr[0], a0); a0 = fmaf(c4.x, wr[1], a0); a0 = fmaf(c4.y, wr[2], a0);
        a1 = fmaf(c4.x, wr[0], a1); a1 = fmaf(c4.y, wr[1], a1); a1 = fmaf(c4.z, wr[2], a1);
        a2 = fmaf(c4.y, wr[0], a2); a2 = fmaf(c4.z, wr[1], a2); a2 = fmaf(c4.w, wr[2], a2);
        a3 = fmaf(c4.z, wr[0], a3); a3 = fmaf(c4.w, wr[1], a3); a3 = fmaf(cr,   wr[2], a3);
    }
    const float s  = g2[c] * rsqrtf(v2[c] + EPSV);
    const float sh = fmaf(-m2[c], s, b2[c]);
    const int gi = c / 40;
    const int cs = (c - gi * 40) * 3 + gi;            // channel shuffle
    float4 o;
    o.x = fmaf(a0, s, sh); o.y = fmaf(a1, s, sh);
    o.z = fmaf(a2, s, sh); o.w = fmaf(a3, s, sh);
    *reinterpret_cast<float4*>(tmp2 + (size_t)(b * MID + cs) * HWP + hw) = o;
}

// ---------- K3: 1x1 grouped conv (120->480, G=3) + BN + ReLU + shortcut ----------
// thread: 4 adjacent px, 20 oc.  grid (49, 24)
__global__ __launch_bounds__(256, 4) void k3_conv3(
    const float* __restrict__ tmp2, const float* __restrict__ w3,
    const float* __restrict__ g3,   const float* __restrict__ b3,
    const float* __restrict__ m3,   const float* __restrict__ v3,
    const float* __restrict__ x,    float* __restrict__ out)
{
    const int t   = blockIdx.x * 256 + threadIdx.x;   // 0..12543
    const int b   = t / 196;
    const int hw  = (t - b * 196) * 4;
    const int oc0 = blockIdx.y * 20;                  // uniform
    const int g   = oc0 / 160;
    const float* __restrict__ ip = tmp2 + (size_t)(b * MID + g * 40) * HWP + hw;
    const float* __restrict__ wp = w3 + oc0 * 40;

    float acc[20][4];
#pragma unroll
    for (int j = 0; j < 20; ++j)
#pragma unroll
        for (int k = 0; k < 4; ++k) acc[j][k] = 0.f;

#pragma unroll 4
    for (int ic = 0; ic < 40; ++ic) {
        const float4 xv = *reinterpret_cast<const float4*>(ip + ic * HWP);
#pragma unroll
        for (int j = 0; j < 20; ++j) {
            const float w = wp[j * 40 + ic];          // scalar load
            acc[j][0] = fmaf(xv.x, w, acc[j][0]);
            acc[j][1] = fmaf(xv.y, w, acc[j][1]);
            acc[j][2] = fmaf(xv.z, w, acc[j][2]);
            acc[j][3] = fmaf(xv.w, w, acc[j][3]);
        }
    }

    const float* __restrict__ sp = x   + (size_t)(b * CIN + oc0) * HWP + hw;
    float*       __restrict__ op = out + (size_t)(b * CIN + oc0) * HWP + hw;
#pragma unroll
    for (int j = 0; j < 20; ++j) {
        const int oc = oc0 + j;
        const float s  = g3[oc] * rsqrtf(v3[oc] + EPSV);
        const float sh = fmaf(-m3[oc], s, b3[oc]);
        const float4 sc = *reinterpret_cast<const float4*>(sp + j * HWP);
        float4 o;
        o.x = fmaf(acc[j][0], s, sh); o.x = (o.x > 0.f ? o.x : 0.f) + sc.x;
        o.y = fmaf(acc[j][1], s, sh); o.y = (o.y > 0.f ? o.y : 0.f) + sc.y;
        o.z = fmaf(acc[j][2], s, sh); o.z = (o.z > 0.f ? o.z : 0.f) + sc.z;
        o.w = fmaf(acc[j][3], s, sh); o.w = (o.w > 0.f ? o.w : 0.f) + sc.w;
        *reinterpret_cast<float4*>(op + j * HWP) = o;
    }
}

extern "C" void kernel_launch(void* const* d_in, const int* in_sizes, int n_in,
                              void* d_out, int out_size, void* d_ws, size_t ws_size,
                              hipStream_t stream) {
    const float* x  = (const float*)d_in[0];
    const float* w1 = (const float*)d_in[1];
    const float* g1 = (const float*)d_in[2];
    const float* b1 = (const float*)d_in[3];
    const float* m1 = (const float*)d_in[4];
    const float* v1 = (const float*)d_in[5];
    const float* w2 = (const float*)d_in[6];
    const float* g2 = (const float*)d_in[7];
    const float* b2 = (const float*)d_in[8];
    const float* m2 = (const float*)d_in[9];
    const float* v2 = (const float*)d_in[10];
    const float* w3 = (const float*)d_in[11];
    const float* g3 = (const float*)d_in[12];
    const float* b3 = (const float*)d_in[13];
    const float* m3 = (const float*)d_in[14];
    const float* v3 = (const float*)d_in[15];
    float* out = (float*)d_out;

    float* tmp1 = (float*)d_ws;                       // 24.1 MB
    float* tmp2 = tmp1 + (size_t)64 * MID * HWP;      // 24.1 MB

    k1_conv1<<<dim3(98, 12),  256, 0, stream>>>(x, w1, g1, b1, m1, v1, tmp1);
    k2_dw   <<<dim3(49, 120), 256, 0, stream>>>(tmp1, w2, g2, b2, m2, v2, tmp2);
    k3_conv3<<<dim3(49, 24),  256, 0, stream>>>(tmp2, w3, g3, b3, m3, v3, x, out);
}

// Round 4
// 126.062 us; speedup vs baseline: 3.0833x; 1.0926x over previous
//
#include <hip/hip_runtime.h>

// ShuffleNet unit, fp32, NCHW. B=64, Cin=Cout=480, mid=120, H=W=28.
// 3 kernels; intermediates in d_ws. Each block computes ALL oc of one group
// for its pixel tile -> inputs are read from HBM exactly once.
// Weights reached via scalar (SGPR) loads: blockIdx-derived or readfirstlane.

namespace {
constexpr int CIN = 480;
constexpr int MID = 120;
constexpr int HWP = 784;
constexpr float EPSV = 1e-5f;
}

// ---------- K1: 1x1 grouped conv (480->120, G=3) + BN + ReLU ----------
// block: 128 thr, 256 px tile, all 40 oc of group blockIdx.y. grid (196, 3)
__global__ __launch_bounds__(128) void k1_conv1(
    const float* __restrict__ x,  const float* __restrict__ w1,
    const float* __restrict__ g1, const float* __restrict__ b1,
    const float* __restrict__ m1, const float* __restrict__ v1,
    float* __restrict__ tmp1)
{
    const int p   = blockIdx.x * 256 + threadIdx.x * 2;   // global px pair
    const int b   = p / HWP;
    const int hw  = p - b * HWP;
    const int g   = blockIdx.y;
    const int oc0 = g * 40;                               // compile-time uniform
    const float* __restrict__ xp = x + (size_t)(b * CIN + g * 160) * HWP + hw;
    const float* __restrict__ wp = w1 + (size_t)oc0 * 160;

    float acc0[40], acc1[40];
#pragma unroll
    for (int j = 0; j < 40; ++j) { acc0[j] = 0.f; acc1[j] = 0.f; }

#pragma unroll 2
    for (int ic = 0; ic < 160; ++ic) {
        const float2 xv = *reinterpret_cast<const float2*>(xp + (size_t)ic * HWP);
#pragma unroll
        for (int j = 0; j < 40; ++j) {
            const float w = wp[j * 160 + ic];             // SGPR load
            acc0[j] = fmaf(xv.x, w, acc0[j]);
            acc1[j] = fmaf(xv.y, w, acc1[j]);
        }
    }

    float* __restrict__ op = tmp1 + (size_t)(b * MID + oc0) * HWP + hw;
#pragma unroll
    for (int j = 0; j < 40; ++j) {
        const int oc = oc0 + j;
        const float s  = g1[oc] * rsqrtf(v1[oc] + EPSV);
        const float sh = fmaf(-m1[oc], s, b1[oc]);
        float2 o;
        o.x = fmaf(acc0[j], s, sh); o.x = o.x > 0.f ? o.x : 0.f;
        o.y = fmaf(acc1[j], s, sh); o.y = o.y > 0.f ? o.y : 0.f;
        *reinterpret_cast<float2*>(op + (size_t)j * HWP) = o;
    }
}

// ---------- K2: depthwise 3x3 + BN, shuffle folded into write ----------
// thread: 4 adjacent px (same row), 1 channel. grid (49, 120)
__global__ __launch_bounds__(256) void k2_dw(
    const float* __restrict__ tmp1, const float* __restrict__ w2,
    const float* __restrict__ g2,   const float* __restrict__ b2,
    const float* __restrict__ m2,   const float* __restrict__ v2,
    float* __restrict__ tmp2)
{
    const int t  = blockIdx.x * 256 + threadIdx.x;        // 0..12543
    const int b  = t / 196;
    const int hw = (t - b * 196) * 4;
    const int h  = hw / 28;
    const int w  = hw - h * 28;                           // 0,4,...,24
    const int c  = blockIdx.y;                            // uniform
    const float* __restrict__ in = tmp1 + (size_t)(b * MID + c) * HWP;

    float wk[9];
#pragma unroll
    for (int i = 0; i < 9; ++i) wk[i] = w2[c * 9 + i];    // SGPR loads

    float a0 = 0.f, a1 = 0.f, a2 = 0.f, a3 = 0.f;
#pragma unroll
    for (int dh = -1; dh <= 1; ++dh) {
        const int hh = h + dh;
        if (hh < 0 || hh > 27) continue;
        const float* r = in + hh * 28 + w;
        const float4 c4 = *reinterpret_cast<const float4*>(r);
        const float cl = (w > 0)  ? r[-1] : 0.f;
        const float cr = (w < 24) ? r[4]  : 0.f;
        const float* wr = wk + (dh + 1) * 3;
        a0 = fmaf(cl,   wr[0], a0); a0 = fmaf(c4.x, wr[1], a0); a0 = fmaf(c4.y, wr[2], a0);
        a1 = fmaf(c4.x, wr[0], a1); a1 = fmaf(c4.y, wr[1], a1); a1 = fmaf(c4.z, wr[2], a1);
        a2 = fmaf(c4.y, wr[0], a2); a2 = fmaf(c4.z, wr[1], a2); a2 = fmaf(c4.w, wr[2], a2);
        a3 = fmaf(c4.z, wr[0], a3); a3 = fmaf(c4.w, wr[1], a3); a3 = fmaf(cr,   wr[2], a3);
    }
    const float s  = g2[c] * rsqrtf(v2[c] + EPSV);
    const float sh = fmaf(-m2[c], s, b2[c]);
    const int gi = c / 40;
    const int cs = (c - gi * 40) * 3 + gi;                // channel shuffle
    float4 o;
    o.x = fmaf(a0, s, sh); o.y = fmaf(a1, s, sh);
    o.z = fmaf(a2, s, sh); o.w = fmaf(a3, s, sh);
    *reinterpret_cast<float4*>(tmp2 + (size_t)(b * MID + cs) * HWP + hw) = o;
}

// ---------- K3: 1x1 grouped conv (120->480) + BN + ReLU + shortcut ----------
// block: 256 thr = 4 waves, 128 px tile; wave w -> oc [g*160+w*40, +40).
// grid (392, 3)
__global__ __launch_bounds__(256) void k3_conv3(
    const float* __restrict__ tmp2, const float* __restrict__ w3,
    const float* __restrict__ g3,   const float* __restrict__ b3,
    const float* __restrict__ m3,   const float* __restrict__ v3,
    const float* __restrict__ x,    float* __restrict__ out)
{
    const int lane = threadIdx.x & 63;
    const int wv   = threadIdx.x >> 6;
    const int p    = blockIdx.x * 128 + lane * 2;         // global px pair
    const int b    = p / HWP;
    const int hw   = p - b * HWP;
    const int g    = blockIdx.y;
    int oc0 = g * 160 + wv * 40;
    oc0 = __builtin_amdgcn_readfirstlane(oc0);            // force SGPR weight path

    const float* __restrict__ ip = tmp2 + (size_t)(b * MID + g * 40) * HWP + hw;
    const float* __restrict__ wp = w3 + (size_t)oc0 * 40;

    float acc0[40], acc1[40];
#pragma unroll
    for (int j = 0; j < 40; ++j) { acc0[j] = 0.f; acc1[j] = 0.f; }

#pragma unroll 4
    for (int ic = 0; ic < 40; ++ic) {
        const float2 xv = *reinterpret_cast<const float2*>(ip + (size_t)ic * HWP);
#pragma unroll
        for (int j = 0; j < 40; ++j) {
            const float w = wp[j * 40 + ic];              // SGPR load
            acc0[j] = fmaf(xv.x, w, acc0[j]);
            acc1[j] = fmaf(xv.y, w, acc1[j]);
        }
    }

    const float* __restrict__ sp = x   + (size_t)(b * CIN + oc0) * HWP + hw;
    float*       __restrict__ op = out + (size_t)(b * CIN + oc0) * HWP + hw;
#pragma unroll
    for (int j = 0; j < 40; ++j) {
        const int oc = oc0 + j;
        const float s  = g3[oc] * rsqrtf(v3[oc] + EPSV);
        const float sh = fmaf(-m3[oc], s, b3[oc]);
        const float2 sc = *reinterpret_cast<const float2*>(sp + (size_t)j * HWP);
        float2 o;
        o.x = fmaf(acc0[j], s, sh); o.x = (o.x > 0.f ? o.x : 0.f) + sc.x;
        o.y = fmaf(acc1[j], s, sh); o.y = (o.y > 0.f ? o.y : 0.f) + sc.y;
        *reinterpret_cast<float2*>(op + (size_t)j * HWP) = o;
    }
}

extern "C" void kernel_launch(void* const* d_in, const int* in_sizes, int n_in,
                              void* d_out, int out_size, void* d_ws, size_t ws_size,
                              hipStream_t stream) {
    const float* x  = (const float*)d_in[0];
    const float* w1 = (const float*)d_in[1];
    const float* g1 = (const float*)d_in[2];
    const float* b1 = (const float*)d_in[3];
    const float* m1 = (const float*)d_in[4];
    const float* v1 = (const float*)d_in[5];
    const float* w2 = (const float*)d_in[6];
    const float* g2 = (const float*)d_in[7];
    const float* b2 = (const float*)d_in[8];
    const float* m2 = (const float*)d_in[9];
    const float* v2 = (const float*)d_in[10];
    const float* w3 = (const float*)d_in[11];
    const float* g3 = (const float*)d_in[12];
    const float* b3 = (const float*)d_in[13];
    const float* m3 = (const float*)d_in[14];
    const float* v3 = (const float*)d_in[15];
    float* out = (float*)d_out;

    float* tmp1 = (float*)d_ws;                           // 24.1 MB
    float* tmp2 = tmp1 + (size_t)64 * MID * HWP;          // 24.1 MB

    k1_conv1<<<dim3(196, 3), 128, 0, stream>>>(x, w1, g1, b1, m1, v1, tmp1);
    k2_dw   <<<dim3(49, 120), 256, 0, stream>>>(tmp1, w2, g2, b2, m2, v2, tmp2);
    k3_conv3<<<dim3(392, 3), 256, 0, stream>>>(tmp2, w3, g3, b3, m3, v3, x, out);
}